// Round 6
// baseline (105.155 us; speedup 1.0000x reference)
//
#include <hip/hip_runtime.h>

// out[1024][1024] = relu(a @ feats^T) @ relu(b @ feats^T)^T ; fp32 in/out.
// TWO dispatches (R5 lesson: LDS staging beats direct fragment loads; R2->R5
// calibration: dur = kernel_time + ~60.5us harness overhead, so cut launches):
//   gemm1: [a;b] @ feats^T, split-K(8), M-tile=32 -> fp32 partials (8 x 1MB)
//          512 blocks (2/CU), 2 staged iterations of BK=128, LDS 43.5KB
//   gemm2: fused 8-way partial reduce + relu + bf16 cvt in LDS staging,
//          then 64x64 MFMA out-tile (proven R2 body)

typedef __attribute__((ext_vector_type(8))) __bf16 bf16x8;
typedef __attribute__((ext_vector_type(4))) float floatx4;

#define KD     2048
#define NF     128
#define NA     1024
#define NSPLIT 8
#define KSP    256          // K per split
#define BK     128          // K per staged iteration
#define FKN    (2048 * 128)

static __device__ inline bf16x8 cvt8(float4 u, float4 v) {
    bf16x8 s;
    s[0] = (__bf16)u.x; s[1] = (__bf16)u.y; s[2] = (__bf16)u.z; s[3] = (__bf16)u.w;
    s[4] = (__bf16)v.x; s[5] = (__bf16)v.y; s[6] = (__bf16)v.z; s[7] = (__bf16)v.w;
    return s;
}
static __device__ inline bf16x8 cvt8_relu(float4 u, float4 v) {
    bf16x8 s;
    s[0] = (__bf16)fmaxf(u.x, 0.f); s[1] = (__bf16)fmaxf(u.y, 0.f);
    s[2] = (__bf16)fmaxf(u.z, 0.f); s[3] = (__bf16)fmaxf(u.w, 0.f);
    s[4] = (__bf16)fmaxf(v.x, 0.f); s[5] = (__bf16)fmaxf(v.y, 0.f);
    s[6] = (__bf16)fmaxf(v.z, 0.f); s[7] = (__bf16)fmaxf(v.w, 0.f);
    return s;
}
static __device__ inline void acc4(float4& d, float4 u) {
    d.x += u.x; d.y += u.y; d.z += u.z; d.w += u.w;
}

// ---- gemm1: part[s][2048][128] = X[m0:m0+32, s*256:(s+1)*256] @ F[:, same]^T
// grid (64, 8) = 512 blocks, 256 thr = 4 waves; wave w owns feat cols
// [w*32, w*32+32). Two staged iterations of BK=128.
__global__ __launch_bounds__(256) void gemm1(const float* __restrict__ A,
                                             const float* __restrict__ B,
                                             const float* __restrict__ F,
                                             float* __restrict__ part) {
    __shared__ __bf16 Xs[32 * 136];    // 8.5 KB (stride 136 = 128+8 pad)
    __shared__ __bf16 Fs[128 * 136];   // 34.8 KB

    const int t    = threadIdx.x;
    const int lane = t & 63;
    const int w    = t >> 6;
    const int ln   = lane & 15;
    const int quad = lane >> 4;
    const int q8   = quad * 8;

    const int m0 = blockIdx.x * 32;        // over [a;b] rows
    const int s  = blockIdx.y;
    const int k0 = s * KSP;
    const float* src = (m0 < NA) ? (A + (size_t)m0 * KD)
                                 : (B + (size_t)(m0 - NA) * KD);

    floatx4 acc[2][2];
#pragma unroll
    for (int mt = 0; mt < 2; mt++)
#pragma unroll
        for (int nt = 0; nt < 2; nt++)
            acc[mt][nt] = (floatx4){0.f, 0.f, 0.f, 0.f};

    const int xr = t >> 3, xc = (t & 7) * 16;   // 32 rows x 128 cols, 16 f32/thread
    const int fr = t >> 1, fc = (t & 1) * 64;   // 128 rows x 128 cols, 64 f32/thread

#pragma unroll
    for (int kk = 0; kk < KSP; kk += BK) {
        {
            const float* p = src + (size_t)xr * KD + (k0 + kk + xc);
            float4 u0 = *(const float4*)(p + 0);
            float4 u1 = *(const float4*)(p + 4);
            float4 u2 = *(const float4*)(p + 8);
            float4 u3 = *(const float4*)(p + 12);
            *(bf16x8*)&Xs[xr * 136 + xc]     = cvt8(u0, u1);
            *(bf16x8*)&Xs[xr * 136 + xc + 8] = cvt8(u2, u3);
        }
        {
            const float* p = F + (size_t)fr * KD + (k0 + kk + fc);
#pragma unroll
            for (int j = 0; j < 64; j += 16) {
                float4 u0 = *(const float4*)(p + j + 0);
                float4 u1 = *(const float4*)(p + j + 4);
                float4 u2 = *(const float4*)(p + j + 8);
                float4 u3 = *(const float4*)(p + j + 12);
                *(bf16x8*)&Fs[fr * 136 + fc + j]     = cvt8(u0, u1);
                *(bf16x8*)&Fs[fr * 136 + fc + j + 8] = cvt8(u2, u3);
            }
        }
        __syncthreads();

#pragma unroll
        for (int ks = 0; ks < BK; ks += 32) {
            bf16x8 bfrag[2];
#pragma unroll
            for (int nt = 0; nt < 2; nt++)
                bfrag[nt] = *(const bf16x8*)&Fs[(w * 32 + nt * 16 + ln) * 136 + ks + q8];
#pragma unroll
            for (int mt = 0; mt < 2; mt++) {
                bf16x8 af = *(const bf16x8*)&Xs[(mt * 16 + ln) * 136 + ks + q8];
#pragma unroll
                for (int nt = 0; nt < 2; nt++)
                    acc[mt][nt] = __builtin_amdgcn_mfma_f32_16x16x32_bf16(
                        af, bfrag[nt], acc[mt][nt], 0, 0, 0);
            }
        }
        __syncthreads();
    }

    float* pdst = part + (size_t)s * FKN;
#pragma unroll
    for (int mt = 0; mt < 2; mt++)
#pragma unroll
        for (int nt = 0; nt < 2; nt++)
#pragma unroll
            for (int r = 0; r < 4; r++)
                pdst[(size_t)(m0 + mt * 16 + quad * 4 + r) * NF
                     + (w * 32 + nt * 16 + ln)] = acc[mt][nt][r];
}

// ---- gemm2: out[i][j] = sum_f relu(sum_s pA)[i][f] * relu(sum_s pB)[j][f]
// grid (16,16): 64x64 out tiles; staging fuses the 8-way reduce + relu + cvt.
__global__ __launch_bounds__(256) void gemm2(const float* __restrict__ part,
                                             float* __restrict__ out) {
    __shared__ __bf16 Ps[64 * 136];
    __shared__ __bf16 Qs[64 * 136];

    const int t    = threadIdx.x;
    const int i0   = blockIdx.y * 64;
    const int j0   = blockIdx.x * 64;
    const int lane = t & 63;
    const int w    = t >> 6;
    const int wm   = w & 1;
    const int wn   = w >> 1;
    const int ln   = lane & 15;
    const int quad = lane >> 4;
    const int q8   = quad * 8;

    // stage with fused reduction: 64 rows x 128 cols each of P (a-side) and Q
    const int prow = t >> 2, pcol = (t & 3) * 32;
    {
        const size_t pbase = (size_t)(i0 + prow) * NF + pcol;
        const size_t qbase = (size_t)(NA + j0 + prow) * NF + pcol;
#pragma unroll
        for (int c = 0; c < 32; c += 8) {
            float4 p0 = make_float4(0.f, 0.f, 0.f, 0.f), p1 = p0;
            float4 q0 = p0, q1 = p0;
#pragma unroll
            for (int s = 0; s < NSPLIT; s++) {
                const float* pp = part + (size_t)s * FKN + pbase + c;
                const float* qq = part + (size_t)s * FKN + qbase + c;
                acc4(p0, *(const float4*)(pp + 0));
                acc4(p1, *(const float4*)(pp + 4));
                acc4(q0, *(const float4*)(qq + 0));
                acc4(q1, *(const float4*)(qq + 4));
            }
            *(bf16x8*)&Ps[prow * 136 + pcol + c] = cvt8_relu(p0, p1);
            *(bf16x8*)&Qs[prow * 136 + pcol + c] = cvt8_relu(q0, q1);
        }
    }
    __syncthreads();

    floatx4 acc[2][2];
#pragma unroll
    for (int mt = 0; mt < 2; mt++)
#pragma unroll
        for (int nt = 0; nt < 2; nt++)
            acc[mt][nt] = (floatx4){0.f, 0.f, 0.f, 0.f};

#pragma unroll
    for (int k0 = 0; k0 < NF; k0 += 32) {
        bf16x8 af[2], bf[2];
#pragma unroll
        for (int mt = 0; mt < 2; mt++)
            af[mt] = *(const bf16x8*)&Ps[(wm * 32 + mt * 16 + ln) * 136 + k0 + q8];
#pragma unroll
        for (int nt = 0; nt < 2; nt++)
            bf[nt] = *(const bf16x8*)&Qs[(wn * 32 + nt * 16 + ln) * 136 + k0 + q8];
#pragma unroll
        for (int mt = 0; mt < 2; mt++)
#pragma unroll
            for (int nt = 0; nt < 2; nt++)
                acc[mt][nt] = __builtin_amdgcn_mfma_f32_16x16x32_bf16(
                    af[mt], bf[nt], acc[mt][nt], 0, 0, 0);
    }

#pragma unroll
    for (int mt = 0; mt < 2; mt++)
#pragma unroll
        for (int nt = 0; nt < 2; nt++)
#pragma unroll
            for (int r = 0; r < 4; r++) {
                int row = i0 + wm * 32 + mt * 16 + quad * 4 + r;
                int col = j0 + wn * 32 + nt * 16 + ln;
                out[(size_t)row * 1024 + col] = acc[mt][nt][r];
            }
}

extern "C" void kernel_launch(void* const* d_in, const int* in_sizes, int n_in,
                              void* d_out, int out_size, void* d_ws, size_t ws_size,
                              hipStream_t stream) {
    const float* a     = (const float*)d_in[0];
    const float* b     = (const float*)d_in[1];
    const float* feats = (const float*)d_in[2];
    float* out  = (float*)d_out;
    float* part = (float*)d_ws;      // 8 x 1 MB fp32 partials

    gemm1<<<dim3(64, NSPLIT), 256, 0, stream>>>(a, b, feats, part);
    gemm2<<<dim3(16, 16), 256, 0, stream>>>(part, out);
}

// Round 7
// 104.873 us; speedup vs baseline: 1.0027x; 1.0027x over previous
//
#include <hip/hip_runtime.h>

// out[1024][1024] = relu(a @ feats^T) @ relu(b @ feats^T)^T ; fp32 in/out.
// TWO dispatches:
//   gemm1: [a;b] @ feats^T, split-K(16), M-tile=64, BK=64 -> fp32 partials;
//          per-mtile LAST-ARRIVER epilogue (device-scope ctr, no polling)
//          reduces the 16 slabs + relu + cvt -> bf16 fkb[2048][128].
//   gemm2: fkb_a @ fkb_b^T (R2's proven body) -> out.
// R6 lessons: fused-redundant reduce in gemm2 = 128MB L3 reads (+20us) - never
// again; M-tile 32 doubles staging per MFMA. R3/R4: no grid barriers/polling.

typedef __attribute__((ext_vector_type(8))) __bf16 bf16x8;
typedef __attribute__((ext_vector_type(4))) __bf16 bf16x4;
typedef __attribute__((ext_vector_type(4))) float floatx4;

#define KD     2048
#define NF     128
#define NA     1024
#define NSPLIT 16
#define KSP    128          // K per split
#define BK     64           // K per staged iteration (2 iters)
#define FKN    (2048 * 128)
#define XSTR   72           // LDS leading dim for BK=64 (+8 pad, 2-way-bank free)

static __device__ inline bf16x8 cvt8(float4 u, float4 v) {
    bf16x8 s;
    s[0] = (__bf16)u.x; s[1] = (__bf16)u.y; s[2] = (__bf16)u.z; s[3] = (__bf16)u.w;
    s[4] = (__bf16)v.x; s[5] = (__bf16)v.y; s[6] = (__bf16)v.z; s[7] = (__bf16)v.w;
    return s;
}
static __device__ inline void acc4(float4& d, float4 u) {
    d.x += u.x; d.y += u.y; d.z += u.z; d.w += u.w;
}

// ---- gemm1 + fused last-arriver reduction ----
// grid (32, 16): x = mtile (64 rows of [a;b]), y = K-split. 256 thr = 4 waves;
// wave w owns feat cols [w*32, w*32+32).
__global__ __launch_bounds__(256) void gemm1(const float* __restrict__ A,
                                             const float* __restrict__ B,
                                             const float* __restrict__ F,
                                             float* __restrict__ part,
                                             unsigned* __restrict__ ctr,
                                             __bf16* __restrict__ fkb) {
    __shared__ __bf16 Xs[64 * XSTR];    // 9.2 KB
    __shared__ __bf16 Fs[128 * XSTR];   // 18.4 KB
    __shared__ int isred;

    const int t    = threadIdx.x;
    const int lane = t & 63;
    const int w    = t >> 6;
    const int ln   = lane & 15;
    const int quad = lane >> 4;
    const int q8   = quad * 8;

    const int mtile = blockIdx.x;
    const int m0    = mtile * 64;
    const int s     = blockIdx.y;
    const int k0    = s * KSP;
    const float* src = (m0 < NA) ? (A + (size_t)m0 * KD)
                                 : (B + (size_t)(m0 - NA) * KD);

    floatx4 acc[4][2];
#pragma unroll
    for (int mt = 0; mt < 4; mt++)
#pragma unroll
        for (int nt = 0; nt < 2; nt++)
            acc[mt][nt] = (floatx4){0.f, 0.f, 0.f, 0.f};

    const int xr = t >> 2, xc = (t & 3) * 16;   // 64 rows x 64 cols, 16 f32/thr
    const int fr = t >> 1, fc = (t & 1) * 32;   // 128 rows x 64 cols, 32 f32/thr

#pragma unroll
    for (int kk = 0; kk < KSP; kk += BK) {
        {
            const float* p = src + (size_t)xr * KD + (k0 + kk + xc);
            float4 u0 = *(const float4*)(p + 0);
            float4 u1 = *(const float4*)(p + 4);
            float4 u2 = *(const float4*)(p + 8);
            float4 u3 = *(const float4*)(p + 12);
            *(bf16x8*)&Xs[xr * XSTR + xc]     = cvt8(u0, u1);
            *(bf16x8*)&Xs[xr * XSTR + xc + 8] = cvt8(u2, u3);
        }
        {
            const float* p = F + (size_t)fr * KD + (k0 + kk + fc);
#pragma unroll
            for (int j = 0; j < 32; j += 16) {
                float4 u0 = *(const float4*)(p + j + 0);
                float4 u1 = *(const float4*)(p + j + 4);
                float4 u2 = *(const float4*)(p + j + 8);
                float4 u3 = *(const float4*)(p + j + 12);
                *(bf16x8*)&Fs[fr * XSTR + fc + j]     = cvt8(u0, u1);
                *(bf16x8*)&Fs[fr * XSTR + fc + j + 8] = cvt8(u2, u3);
            }
        }
        __syncthreads();

#pragma unroll
        for (int ks = 0; ks < BK; ks += 32) {
            bf16x8 bfrag[2];
#pragma unroll
            for (int nt = 0; nt < 2; nt++)
                bfrag[nt] = *(const bf16x8*)&Fs[(w * 32 + nt * 16 + ln) * XSTR + ks + q8];
#pragma unroll
            for (int mt = 0; mt < 4; mt++) {
                bf16x8 af = *(const bf16x8*)&Xs[(mt * 16 + ln) * XSTR + ks + q8];
#pragma unroll
                for (int nt = 0; nt < 2; nt++)
                    acc[mt][nt] = __builtin_amdgcn_mfma_f32_16x16x32_bf16(
                        af, bfrag[nt], acc[mt][nt], 0, 0, 0);
            }
        }
        __syncthreads();
    }

    // store this split's fp32 slab
    float* pdst = part + (size_t)s * FKN;
#pragma unroll
    for (int mt = 0; mt < 4; mt++)
#pragma unroll
        for (int nt = 0; nt < 2; nt++)
#pragma unroll
            for (int r = 0; r < 4; r++)
                pdst[(size_t)(m0 + mt * 16 + quad * 4 + r) * NF
                     + (w * 32 + nt * 16 + ln)] = acc[mt][nt][r];

    // ---- last-arriver reduction for this mtile (no polling, deadlock-free) ----
    __syncthreads();                        // all block stores drained (vmcnt0)
    if (t == 0) {
        __threadfence();                    // release our slab (XCD L2 -> coherent)
        unsigned old = __hip_atomic_fetch_add(&ctr[mtile * 32], 1u,
                           __ATOMIC_RELAXED, __HIP_MEMORY_SCOPE_AGENT);
        int red = (old == NSPLIT - 1);
        if (red) __threadfence();           // acquire: all 16 slabs visible
        isred = red;
    }
    __syncthreads();                        // broadcast decision (+ acquire h-b)
    if (!isred) return;

    // reduce 16 slabs of this mtile: 64x128 f32 -> relu -> bf16 fkb slab
#pragma unroll
    for (int i = 0; i < 8; i++) {
        int f   = i * 256 + t;              // float4 index within slab (0..2047)
        int row = f >> 5;
        int c4  = (f & 31) * 4;
        size_t off = (size_t)(m0 + row) * NF + c4;
        float4 sum = make_float4(0.f, 0.f, 0.f, 0.f);
#pragma unroll
        for (int ss = 0; ss < NSPLIT; ss++)
            acc4(sum, *(const float4*)(part + (size_t)ss * FKN + off));
        bf16x4 o;
        o[0] = (__bf16)fmaxf(sum.x, 0.f);
        o[1] = (__bf16)fmaxf(sum.y, 0.f);
        o[2] = (__bf16)fmaxf(sum.z, 0.f);
        o[3] = (__bf16)fmaxf(sum.w, 0.f);
        *(bf16x4*)(fkb + off) = o;
    }
}

// ---- gemm2: out[i][j] = sum_f fkb[i][f] * fkb[1024+j][f] (R2 body) ----
__global__ __launch_bounds__(256) void gemm2(const __bf16* __restrict__ fkb,
                                             float* __restrict__ out) {
    __shared__ __bf16 Ps[64 * 136];
    __shared__ __bf16 Qs[64 * 136];

    const int t    = threadIdx.x;
    const int i0   = blockIdx.y * 64;
    const int j0   = blockIdx.x * 64;
    const int lane = t & 63;
    const int w    = t >> 6;
    const int wm   = w & 1;
    const int wn   = w >> 1;
    const int ln   = lane & 15;
    const int quad = lane >> 4;
    const int q8   = quad * 8;

    const int prow = t >> 2, pcol = (t & 3) * 32;
    {
        const __bf16* p = fkb + (size_t)(i0 + prow) * NF + pcol;
        const __bf16* q = fkb + (size_t)(NA + j0 + prow) * NF + pcol;
#pragma unroll
        for (int c = 0; c < 32; c += 8) {
            *(bf16x8*)&Ps[prow * 136 + pcol + c] = *(const bf16x8*)(p + c);
            *(bf16x8*)&Qs[prow * 136 + pcol + c] = *(const bf16x8*)(q + c);
        }
    }
    __syncthreads();

    floatx4 acc[2][2];
#pragma unroll
    for (int mt = 0; mt < 2; mt++)
#pragma unroll
        for (int nt = 0; nt < 2; nt++)
            acc[mt][nt] = (floatx4){0.f, 0.f, 0.f, 0.f};

#pragma unroll
    for (int k0 = 0; k0 < NF; k0 += 32) {
        bf16x8 af[2], bf[2];
#pragma unroll
        for (int mt = 0; mt < 2; mt++)
            af[mt] = *(const bf16x8*)&Ps[(wm * 32 + mt * 16 + ln) * 136 + k0 + q8];
#pragma unroll
        for (int nt = 0; nt < 2; nt++)
            bf[nt] = *(const bf16x8*)&Qs[(wn * 32 + nt * 16 + ln) * 136 + k0 + q8];
#pragma unroll
        for (int mt = 0; mt < 2; mt++)
#pragma unroll
            for (int nt = 0; nt < 2; nt++)
                acc[mt][nt] = __builtin_amdgcn_mfma_f32_16x16x32_bf16(
                    af[mt], bf[nt], acc[mt][nt], 0, 0, 0);
    }

#pragma unroll
    for (int mt = 0; mt < 2; mt++)
#pragma unroll
        for (int nt = 0; nt < 2; nt++)
#pragma unroll
            for (int r = 0; r < 4; r++) {
                int row = i0 + wm * 32 + mt * 16 + quad * 4 + r;
                int col = j0 + wn * 32 + nt * 16 + ln;
                out[(size_t)row * 1024 + col] = acc[mt][nt][r];
            }
}

extern "C" void kernel_launch(void* const* d_in, const int* in_sizes, int n_in,
                              void* d_out, int out_size, void* d_ws, size_t ws_size,
                              hipStream_t stream) {
    const float* a     = (const float*)d_in[0];
    const float* b     = (const float*)d_in[1];
    const float* feats = (const float*)d_in[2];
    float* out = (float*)d_out;

    float*    part = (float*)d_ws;                               // 16 x 1MB fp32
    unsigned* ctr  = (unsigned*)((char*)d_ws + (size_t)NSPLIT * FKN * 4);     // 4KB
    __bf16*   fkb  = (__bf16*)((char*)d_ws + (size_t)NSPLIT * FKN * 4 + 8192); // 512KB

    hipMemsetAsync(ctr, 0, 4096, stream);
    gemm1<<<dim3(32, NSPLIT), 256, 0, stream>>>(a, b, feats, part, ctr, fkb);
    gemm2<<<dim3(16, 16), 256, 0, stream>>>(fkb, out);
}